// Round 1
// baseline (524.748 us; speedup 1.0000x reference)
//
#include <hip/hip_runtime.h>

#define NB 8192
#define NK 1024
#define ND 2048
#define BK 16
#define LDS_STRIDE 20   // 16 + pad4: 80B row stride, 16B-aligned, breaks pow2 bank pattern

// ---------------- kernel 0: codebook squared norms ----------------
__global__ void enorm_kernel(const float* __restrict__ e, float* __restrict__ enorm) {
    const int k = blockIdx.x;          // 1024 blocks
    const int lane = threadIdx.x;      // 64 threads
    const float4* row = (const float4*)(e + (size_t)k * ND);
    float s = 0.f;
#pragma unroll
    for (int i = 0; i < 8; ++i) {
        float4 v = row[lane + 64 * i];
        s += v.x * v.x + v.y * v.y + v.z * v.z + v.w * v.w;
    }
#pragma unroll
    for (int m = 32; m; m >>= 1) s += __shfl_xor(s, m, 64);
    if (lane == 0) enorm[k] = s;
}

// ---------------- kernel 1: f32 distance GEMM + per-chunk argmin ----------------
// block tile: 128 rows x 128 codes; 256 threads (tx 0..31, ty 0..7); thread tile 16x4.
// score[b,k] = ||e_k||^2 - 2 z_b . e_k  (row-constant ||z||^2 dropped; argmin unchanged)
__global__ __launch_bounds__(256, 2)
void argmin_kernel(const float* __restrict__ z, const float* __restrict__ e,
                   const float* __restrict__ enorm,
                   float* __restrict__ pminv, int* __restrict__ pmini) {
    __shared__ float zs[128 * LDS_STRIDE];
    __shared__ float es[128 * LDS_STRIDE];
    const int t  = threadIdx.x;
    const int tx = t & 31;
    const int ty = t >> 5;
    const int rowBase = blockIdx.x * 128;
    const int colBase = blockIdx.y * 128;

    float acc[16][4];
#pragma unroll
    for (int i = 0; i < 16; ++i)
#pragma unroll
        for (int j = 0; j < 4; ++j) acc[i][j] = 0.f;

    const int srow = t >> 2;   // 0..63 (staging row, two passes of 64)
    const int sc4  = t & 3;    // which float4 within the 16-float row chunk

    for (int k0 = 0; k0 < ND; k0 += BK) {
        // stage z & e tiles: 128 rows x 16 floats each, float4 global loads + b128 LDS writes
#pragma unroll
        for (int q = 0; q < 2; ++q) {
            int r = srow + 64 * q;
            float4 vz = *(const float4*)(z + (size_t)(rowBase + r) * ND + k0 + sc4 * 4);
            *(float4*)(zs + r * LDS_STRIDE + sc4 * 4) = vz;
            float4 ve = *(const float4*)(e + (size_t)(colBase + r) * ND + k0 + sc4 * 4);
            *(float4*)(es + r * LDS_STRIDE + sc4 * 4) = ve;
        }
        __syncthreads();
#pragma unroll
        for (int g = 0; g < BK / 4; ++g) {
            float4 ef[4];
#pragma unroll
            for (int j = 0; j < 4; ++j)
                ef[j] = *(const float4*)(es + (tx + 32 * j) * LDS_STRIDE + g * 4);
#pragma unroll
            for (int i = 0; i < 16; ++i) {
                // same address for all 32 tx lanes -> LDS broadcast, ~free
                float4 zf = *(const float4*)(zs + (ty + 8 * i) * LDS_STRIDE + g * 4);
#pragma unroll
                for (int j = 0; j < 4; ++j) {
                    acc[i][j] += zf.x * ef[j].x;
                    acc[i][j] += zf.y * ef[j].y;
                    acc[i][j] += zf.z * ef[j].z;
                    acc[i][j] += zf.w * ef[j].w;
                }
            }
        }
        __syncthreads();
    }

    // epilogue: per-row argmin over this block's 128 codes (tie -> lowest index,
    // matching jnp.argmin first-occurrence semantics)
#pragma unroll
    for (int i = 0; i < 16; ++i) {
        float bv = 3.0e38f; int bi = 0x7fffffff;
#pragma unroll
        for (int j = 0; j < 4; ++j) {           // j ascending => code index ascending
            int cg = colBase + tx + 32 * j;
            float s = enorm[cg] - 2.0f * acc[i][j];
            if (s < bv) { bv = s; bi = cg; }
        }
#pragma unroll
        for (int m = 16; m; m >>= 1) {          // xor<32 stays within the 32-lane tx half
            float ov = __shfl_xor(bv, m, 64);
            int   oi = __shfl_xor(bi, m, 64);
            if (ov < bv || (ov == bv && oi < bi)) { bv = ov; bi = oi; }
        }
        if (tx == 0) {
            int r = rowBase + ty + 8 * i;
            pminv[(size_t)r * 8 + blockIdx.y] = bv;
            pmini[(size_t)r * 8 + blockIdx.y] = bi;
        }
    }
}

// ---------------- kernel 2: combine the 8 code-chunk partial argmins ----------------
__global__ void final_argmin_kernel(const float* __restrict__ pminv,
                                    const int* __restrict__ pmini,
                                    int* __restrict__ ind) {
    int b = blockIdx.x * 256 + threadIdx.x;
    if (b >= NB) return;
    float bv = pminv[(size_t)b * 8];
    int   bi = pmini[(size_t)b * 8];
#pragma unroll
    for (int c = 1; c < 8; ++c) {               // chunk ascending => index-order tie-break
        float v  = pminv[(size_t)b * 8 + c];
        int   i2 = pmini[(size_t)b * 8 + c];
        if (v < bv || (v == bv && i2 < bi)) { bv = v; bi = i2; }
    }
    ind[b] = bi;
}

// ---------------- kernel 3: gather z_q, write output, accumulate loss ----------------
__global__ __launch_bounds__(256)
void gather_loss_kernel(const float* __restrict__ z, const float* __restrict__ e,
                        const int* __restrict__ ind, float* __restrict__ out,
                        float* __restrict__ loss) {
    const int NT4 = NB * ND / 4;   // 4,194,304 float4s
    float accm = 0.f;
    for (int f = blockIdx.x * blockDim.x + threadIdx.x; f < NT4;
         f += gridDim.x * blockDim.x) {
        int b  = f >> 9;           // 512 float4 per row
        int k4 = f & 511;
        const float4 q  = *(const float4*)(e + (size_t)ind[b] * ND + (size_t)k4 * 4);
        const float4 zz = *(const float4*)(z + (size_t)f * 4);
        *(float4*)(out + (size_t)f * 4) = q;   // straight-through forward value = z_q
        float dx = q.x - zz.x, dy = q.y - zz.y, dz = q.z - zz.z, dw = q.w - zz.w;
        accm += dx * dx + dy * dy + dz * dz + dw * dw;
    }
#pragma unroll
    for (int m = 32; m; m >>= 1) accm += __shfl_xor(accm, m, 64);
    __shared__ float red[4];
    int lane = threadIdx.x & 63, w = threadIdx.x >> 6;
    if (lane == 0) red[w] = accm;
    __syncthreads();
    if (threadIdx.x == 0) {
        float s = (red[0] + red[1]) + (red[2] + red[3]);
        // forward loss = (0.25*mse + mse) * 10 = 12.5 * sum / (B*N*D)
        atomicAdd(loss, s * (12.5f / 16777216.0f));
    }
}

extern "C" void kernel_launch(void* const* d_in, const int* in_sizes, int n_in,
                              void* d_out, int out_size, void* d_ws, size_t ws_size,
                              hipStream_t stream) {
    const float* z = (const float*)d_in[0];
    const float* e = (const float*)d_in[1];
    float* out = (float*)d_out;
    float* ws  = (float*)d_ws;

    float* enorm = ws;                          // 1024 f
    float* pminv = ws + 1024;                   // 8192*8 f
    int*   pmini = (int*)(ws + 1024 + 65536);   // 8192*8 i
    int*   ind   = (int*)(ws + 1024 + 2 * 65536); // 8192 i
    float* loss  = out + (size_t)NB * ND;

    hipLaunchKernelGGL(enorm_kernel, dim3(NK), dim3(64), 0, stream, e, enorm);
    hipLaunchKernelGGL(argmin_kernel, dim3(NB / 128, NK / 128), dim3(256), 0, stream,
                       z, e, enorm, pminv, pmini);
    hipLaunchKernelGGL(final_argmin_kernel, dim3(NB / 256), dim3(256), 0, stream,
                       pminv, pmini, ind);
    hipMemsetAsync(loss, 0, sizeof(float), stream);
    hipLaunchKernelGGL(gather_loss_kernel, dim3(2048), dim3(256), 0, stream,
                       z, e, ind, out, loss);
}

// Round 2
// 131.474 us; speedup vs baseline: 3.9913x; 3.9913x over previous
//
#include <hip/hip_runtime.h>

#define NB 8192
#define NK 1024
#define ND 2048
#define DELTA 6.0f

typedef __bf16 bf16x8 __attribute__((ext_vector_type(8)));
typedef float f32x4 __attribute__((ext_vector_type(4)));

static __device__ __forceinline__ unsigned short f2bf(float f) {
    unsigned u = __float_as_uint(f);
    unsigned r = (u + 0x7fff + ((u >> 16) & 1)) >> 16;   // RNE
    return (unsigned short)r;
}

static __device__ __forceinline__ void async16(const void* g, void* l) {
    __builtin_amdgcn_global_load_lds(
        (const __attribute__((address_space(1))) void*)g,
        (__attribute__((address_space(3))) void*)l, 16, 0, 0);
}

// ---------------- fast path kernel A: z f32 -> bf16 ----------------
__global__ void conv_z_kernel(const float* __restrict__ z, unsigned short* __restrict__ zh) {
    const int N4 = NB * ND / 4;
    for (int i = blockIdx.x * blockDim.x + threadIdx.x; i < N4; i += gridDim.x * blockDim.x) {
        float4 v = ((const float4*)z)[i];
        ushort4 h;
        h.x = f2bf(v.x); h.y = f2bf(v.y); h.z = f2bf(v.z); h.w = f2bf(v.w);
        ((ushort4*)zh)[i] = h;
    }
}

// ---------------- fast path kernel B: e f32 -> bf16 + ||e||^2 ----------------
__global__ void conv_e_kernel(const float* __restrict__ e, unsigned short* __restrict__ eh,
                              float* __restrict__ enorm) {
    const int k = blockIdx.x;          // 1024 blocks of 64
    const int l = threadIdx.x;
    const float4* row = (const float4*)(e + (size_t)k * ND);
    ushort4* orow = (ushort4*)(eh + (size_t)k * ND);
    float s = 0.f;
#pragma unroll
    for (int i = 0; i < 8; ++i) {
        float4 v = row[l + 64 * i];
        s += v.x * v.x + v.y * v.y + v.z * v.z + v.w * v.w;
        ushort4 h;
        h.x = f2bf(v.x); h.y = f2bf(v.y); h.z = f2bf(v.z); h.w = f2bf(v.w);
        orow[l + 64 * i] = h;
    }
#pragma unroll
    for (int m = 32; m; m >>= 1) s += __shfl_xor(s, m, 64);
    if (l == 0) enorm[k] = s;
}

// ---------------- fast path kernel C: coarse bf16 MFMA GEMM -> S~ ----------------
// S[b][k] = ||e_k||^2 - 2 * zh_b . eh_k   (128x128 tile, BK=32, m97 structure)
__global__ __launch_bounds__(256)
void coarse_gemm_kernel(const unsigned short* __restrict__ zh,
                        const unsigned short* __restrict__ eh,
                        const float* __restrict__ enorm, float* __restrict__ S) {
    __shared__ __align__(16) unsigned short As[128 * 32];
    __shared__ __align__(16) unsigned short Bs[128 * 32];
    const int t = threadIdx.x;
    const int w = t >> 6, l = t & 63;
    const int rowBase = blockIdx.x * 128;
    const int colBase = blockIdx.y * 128;
    const int wr = w & 1, wc = w >> 1;

    f32x4 acc[4][4];
#pragma unroll
    for (int m = 0; m < 4; ++m)
#pragma unroll
        for (int n = 0; n < 4; ++n) acc[m][n] = (f32x4)(0.0f);

    // staging: chunk c = q*256 + w*64 + l covers LDS bytes c*16; row=c>>2, kchunk=c&3
    const int sr = w * 16 + (l >> 2);
    const int skc = (l & 3) * 8;
    const size_t zbase = (size_t)(rowBase + sr) * ND + skc;
    const size_t ebase = (size_t)(colBase + sr) * ND + skc;

    for (int k0 = 0; k0 < ND; k0 += 32) {
#pragma unroll
        for (int q = 0; q < 2; ++q) {
            async16(zh + zbase + (size_t)q * 64 * ND + k0, &As[q * 2048 + w * 512]);
            async16(eh + ebase + (size_t)q * 64 * ND + k0, &Bs[q * 2048 + w * 512]);
        }
        __syncthreads();
        bf16x8 af[4], bfr[4];
#pragma unroll
        for (int m = 0; m < 4; ++m)
            af[m] = *(const bf16x8*)&As[(wr * 64 + m * 16 + (l & 15)) * 32 + (l >> 4) * 8];
#pragma unroll
        for (int n = 0; n < 4; ++n)
            bfr[n] = *(const bf16x8*)&Bs[(wc * 64 + n * 16 + (l & 15)) * 32 + (l >> 4) * 8];
#pragma unroll
        for (int m = 0; m < 4; ++m)
#pragma unroll
            for (int n = 0; n < 4; ++n)
                acc[m][n] = __builtin_amdgcn_mfma_f32_16x16x32_bf16(af[m], bfr[n], acc[m][n], 0, 0, 0);
        __syncthreads();
    }

    // epilogue: C/D layout col = lane&15, row = (lane>>4)*4 + reg  [m89-verified]
#pragma unroll
    for (int n = 0; n < 4; ++n) {
        int col = colBase + wc * 64 + n * 16 + (l & 15);
        float en = enorm[col];
#pragma unroll
        for (int m = 0; m < 4; ++m) {
            int row0 = rowBase + wr * 64 + m * 16 + (l >> 4) * 4;
#pragma unroll
            for (int j = 0; j < 4; ++j)
                S[(size_t)(row0 + j) * NK + col] = en - 2.0f * acc[m][n][j];
        }
    }
}

// ---------------- fast path kernel D: row min + candidate resolve ----------------
// one wave per row; exact f32 rescore only when >1 candidate within DELTA of min
__global__ __launch_bounds__(256)
void resolve_kernel(const float* __restrict__ S, const float* __restrict__ z,
                    const float* __restrict__ e, const float* __restrict__ enorm,
                    int* __restrict__ ind) {
    __shared__ int candk[4][32];
    __shared__ int candn[4];
    const int w = threadIdx.x >> 6, l = threadIdx.x & 63;
    const int b = blockIdx.x * 4 + w;
    if (l == 0) candn[w] = 0;
    __syncthreads();

    const float4* r4 = (const float4*)(S + (size_t)b * NK);
    float4 v[4];
    float m = 3.0e38f;
#pragma unroll
    for (int i = 0; i < 4; ++i) {
        v[i] = r4[l + 64 * i];
        m = fminf(m, fminf(fminf(v[i].x, v[i].y), fminf(v[i].z, v[i].w)));
    }
#pragma unroll
    for (int mm = 32; mm; mm >>= 1) m = fminf(m, __shfl_xor(m, mm, 64));
    const float thr = m + DELTA;

#pragma unroll
    for (int i = 0; i < 4; ++i) {
        int k0 = (l + 64 * i) * 4;
        if (v[i].x <= thr) { int p = atomicAdd(&candn[w], 1); if (p < 32) candk[w][p] = k0; }
        if (v[i].y <= thr) { int p = atomicAdd(&candn[w], 1); if (p < 32) candk[w][p] = k0 + 1; }
        if (v[i].z <= thr) { int p = atomicAdd(&candn[w], 1); if (p < 32) candk[w][p] = k0 + 2; }
        if (v[i].w <= thr) { int p = atomicAdd(&candn[w], 1); if (p < 32) candk[w][p] = k0 + 3; }
    }
    __syncthreads();

    int cnt = candn[w]; if (cnt > 32) cnt = 32;
    int bestk;
    if (cnt == 1) {
        bestk = candk[w][0];
    } else {
        float bestv = 3.0e38f; bestk = 0x7fffffff;
        const float4* z4 = (const float4*)(z + (size_t)b * ND);
        for (int c = 0; c < cnt; ++c) {
            int k = candk[w][c];
            const float4* e4 = (const float4*)(e + (size_t)k * ND);
            float dot = 0.f;
#pragma unroll
            for (int i = 0; i < 8; ++i) {
                float4 a = z4[l + 64 * i], bb = e4[l + 64 * i];
                dot += a.x * bb.x + a.y * bb.y + a.z * bb.z + a.w * bb.w;
            }
#pragma unroll
            for (int mm = 32; mm; mm >>= 1) dot += __shfl_xor(dot, mm, 64);
            float s = enorm[k] - 2.0f * dot;
            if (s < bestv || (s == bestv && k < bestk)) { bestv = s; bestk = k; }
        }
    }
    if (l == 0) ind[b] = bestk;
}

// ---------------- fallback path (round-1, f32 VALU) ----------------
#define BK 16
#define LDS_STRIDE 20

__global__ void enorm_kernel(const float* __restrict__ e, float* __restrict__ enorm) {
    const int k = blockIdx.x;
    const int lane = threadIdx.x;
    const float4* row = (const float4*)(e + (size_t)k * ND);
    float s = 0.f;
#pragma unroll
    for (int i = 0; i < 8; ++i) {
        float4 v = row[lane + 64 * i];
        s += v.x * v.x + v.y * v.y + v.z * v.z + v.w * v.w;
    }
#pragma unroll
    for (int m = 32; m; m >>= 1) s += __shfl_xor(s, m, 64);
    if (lane == 0) enorm[k] = s;
}

__global__ __launch_bounds__(256, 2)
void argmin_kernel(const float* __restrict__ z, const float* __restrict__ e,
                   const float* __restrict__ enorm,
                   float* __restrict__ pminv, int* __restrict__ pmini) {
    __shared__ float zs[128 * LDS_STRIDE];
    __shared__ float es[128 * LDS_STRIDE];
    const int t  = threadIdx.x;
    const int tx = t & 31;
    const int ty = t >> 5;
    const int rowBase = blockIdx.x * 128;
    const int colBase = blockIdx.y * 128;

    float acc[16][4];
#pragma unroll
    for (int i = 0; i < 16; ++i)
#pragma unroll
        for (int j = 0; j < 4; ++j) acc[i][j] = 0.f;

    const int srow = t >> 2;
    const int sc4  = t & 3;

    for (int k0 = 0; k0 < ND; k0 += BK) {
#pragma unroll
        for (int q = 0; q < 2; ++q) {
            int r = srow + 64 * q;
            float4 vz = *(const float4*)(z + (size_t)(rowBase + r) * ND + k0 + sc4 * 4);
            *(float4*)(zs + r * LDS_STRIDE + sc4 * 4) = vz;
            float4 ve = *(const float4*)(e + (size_t)(colBase + r) * ND + k0 + sc4 * 4);
            *(float4*)(es + r * LDS_STRIDE + sc4 * 4) = ve;
        }
        __syncthreads();
#pragma unroll
        for (int g = 0; g < BK / 4; ++g) {
            float4 ef[4];
#pragma unroll
            for (int j = 0; j < 4; ++j)
                ef[j] = *(const float4*)(es + (tx + 32 * j) * LDS_STRIDE + g * 4);
#pragma unroll
            for (int i = 0; i < 16; ++i) {
                float4 zf = *(const float4*)(zs + (ty + 8 * i) * LDS_STRIDE + g * 4);
#pragma unroll
                for (int j = 0; j < 4; ++j) {
                    acc[i][j] += zf.x * ef[j].x;
                    acc[i][j] += zf.y * ef[j].y;
                    acc[i][j] += zf.z * ef[j].z;
                    acc[i][j] += zf.w * ef[j].w;
                }
            }
        }
        __syncthreads();
    }
#pragma unroll
    for (int i = 0; i < 16; ++i) {
        float bv = 3.0e38f; int bi = 0x7fffffff;
#pragma unroll
        for (int j = 0; j < 4; ++j) {
            int cg = colBase + tx + 32 * j;
            float s = enorm[cg] - 2.0f * acc[i][j];
            if (s < bv) { bv = s; bi = cg; }
        }
#pragma unroll
        for (int m = 16; m; m >>= 1) {
            float ov = __shfl_xor(bv, m, 64);
            int   oi = __shfl_xor(bi, m, 64);
            if (ov < bv || (ov == bv && oi < bi)) { bv = ov; bi = oi; }
        }
        if (tx == 0) {
            int r = rowBase + ty + 8 * i;
            pminv[(size_t)r * 8 + blockIdx.y] = bv;
            pmini[(size_t)r * 8 + blockIdx.y] = bi;
        }
    }
}

__global__ void final_argmin_kernel(const float* __restrict__ pminv,
                                    const int* __restrict__ pmini,
                                    int* __restrict__ ind) {
    int b = blockIdx.x * 256 + threadIdx.x;
    if (b >= NB) return;
    float bv = pminv[(size_t)b * 8];
    int   bi = pmini[(size_t)b * 8];
#pragma unroll
    for (int c = 1; c < 8; ++c) {
        float v  = pminv[(size_t)b * 8 + c];
        int   i2 = pmini[(size_t)b * 8 + c];
        if (v < bv || (v == bv && i2 < bi)) { bv = v; bi = i2; }
    }
    ind[b] = bi;
}

// ---------------- shared: gather z_q, write output, accumulate loss ----------------
__global__ __launch_bounds__(256)
void gather_loss_kernel(const float* __restrict__ z, const float* __restrict__ e,
                        const int* __restrict__ ind, float* __restrict__ out,
                        float* __restrict__ loss) {
    const int NT4 = NB * ND / 4;
    float accm = 0.f;
    for (int f = blockIdx.x * blockDim.x + threadIdx.x; f < NT4;
         f += gridDim.x * blockDim.x) {
        int b  = f >> 9;
        int k4 = f & 511;
        const float4 q  = *(const float4*)(e + (size_t)ind[b] * ND + (size_t)k4 * 4);
        const float4 zz = *(const float4*)(z + (size_t)f * 4);
        *(float4*)(out + (size_t)f * 4) = q;
        float dx = q.x - zz.x, dy = q.y - zz.y, dz = q.z - zz.z, dw = q.w - zz.w;
        accm += dx * dx + dy * dy + dz * dz + dw * dw;
    }
#pragma unroll
    for (int m = 32; m; m >>= 1) accm += __shfl_xor(accm, m, 64);
    __shared__ float red[4];
    int lane = threadIdx.x & 63, w = threadIdx.x >> 6;
    if (lane == 0) red[w] = accm;
    __syncthreads();
    if (threadIdx.x == 0) {
        float s = (red[0] + red[1]) + (red[2] + red[3]);
        atomicAdd(loss, s * (12.5f / 16777216.0f));
    }
}

extern "C" void kernel_launch(void* const* d_in, const int* in_sizes, int n_in,
                              void* d_out, int out_size, void* d_ws, size_t ws_size,
                              hipStream_t stream) {
    const float* z = (const float*)d_in[0];
    const float* e = (const float*)d_in[1];
    float* out  = (float*)d_out;
    float* loss = out + (size_t)NB * ND;
    char* W = (char*)d_ws;

    // fast path needs: zh 32MB + eh 4MB + S 32MB + enorm/ind/pad
    const size_t OFF_ZH = 0;
    const size_t OFF_EH = 33554432;
    const size_t OFF_S  = 37748736;
    const size_t OFF_EN = 71303168;
    const size_t OFF_IND = 71307264;
    const size_t NEED_FAST = 71340032 + 32768;

    hipMemsetAsync(loss, 0, sizeof(float), stream);

    if (ws_size >= NEED_FAST) {
        unsigned short* zh = (unsigned short*)(W + OFF_ZH);
        unsigned short* eh = (unsigned short*)(W + OFF_EH);
        float* S     = (float*)(W + OFF_S);
        float* enorm = (float*)(W + OFF_EN);
        int*   ind   = (int*)(W + OFF_IND);

        hipLaunchKernelGGL(conv_z_kernel, dim3(2048), dim3(256), 0, stream, z, zh);
        hipLaunchKernelGGL(conv_e_kernel, dim3(NK), dim3(64), 0, stream, e, eh, enorm);
        hipLaunchKernelGGL(coarse_gemm_kernel, dim3(NB / 128, NK / 128), dim3(256), 0, stream,
                           zh, eh, enorm, S);
        hipLaunchKernelGGL(resolve_kernel, dim3(NB / 4), dim3(256), 0, stream,
                           S, z, e, enorm, ind);
        hipLaunchKernelGGL(gather_loss_kernel, dim3(2048), dim3(256), 0, stream,
                           z, e, ind, out, loss);
    } else {
        float* enorm = (float*)W;                       // 1024 f
        float* pminv = (float*)(W + 4096);              // 65536 f
        int*   pmini = (int*)(W + 4096 + 262144);       // 65536 i
        int*   ind   = (int*)(W + 4096 + 524288);       // 8192 i

        hipLaunchKernelGGL(enorm_kernel, dim3(NK), dim3(64), 0, stream, e, enorm);
        hipLaunchKernelGGL(argmin_kernel, dim3(NB / 128, NK / 128), dim3(256), 0, stream,
                           z, e, enorm, pminv, pmini);
        hipLaunchKernelGGL(final_argmin_kernel, dim3(NB / 256), dim3(256), 0, stream,
                           pminv, pmini, ind);
        hipLaunchKernelGGL(gather_loss_kernel, dim3(2048), dim3(256), 0, stream,
                           z, e, ind, out, loss);
    }
}

// Round 3
// 114.032 us; speedup vs baseline: 4.6018x; 1.1530x over previous
//
#include <hip/hip_runtime.h>

#define NB 8192
#define NK 1024
#define ND 2048
#define DELTA 6.0f

typedef __bf16 bf16x8 __attribute__((ext_vector_type(8)));
typedef float f32x4 __attribute__((ext_vector_type(4)));

static __device__ __forceinline__ unsigned short f2bf(float f) {
    unsigned u = __float_as_uint(f);
    unsigned r = (u + 0x7fff + ((u >> 16) & 1)) >> 16;   // RNE
    return (unsigned short)r;
}

static __device__ __forceinline__ void async16(const void* g, void* l) {
    __builtin_amdgcn_global_load_lds(
        (const __attribute__((address_space(1))) void*)g,
        (__attribute__((address_space(3))) void*)l, 16, 0, 0);
}

// ---------------- fast path kernel A: z f32 -> bf16 ----------------
__global__ void conv_z_kernel(const float* __restrict__ z, unsigned short* __restrict__ zh) {
    const int N4 = NB * ND / 4;
    for (int i = blockIdx.x * blockDim.x + threadIdx.x; i < N4; i += gridDim.x * blockDim.x) {
        float4 v = ((const float4*)z)[i];
        ushort4 h;
        h.x = f2bf(v.x); h.y = f2bf(v.y); h.z = f2bf(v.z); h.w = f2bf(v.w);
        ((ushort4*)zh)[i] = h;
    }
}

// ---------------- fast path kernel B: e f32 -> bf16 + ||e||^2 ----------------
__global__ void conv_e_kernel(const float* __restrict__ e, unsigned short* __restrict__ eh,
                              float* __restrict__ enorm) {
    const int k = blockIdx.x;          // 1024 blocks of 64
    const int l = threadIdx.x;
    const float4* row = (const float4*)(e + (size_t)k * ND);
    ushort4* orow = (ushort4*)(eh + (size_t)k * ND);
    float s = 0.f;
#pragma unroll
    for (int i = 0; i < 8; ++i) {
        float4 v = row[l + 64 * i];
        s += v.x * v.x + v.y * v.y + v.z * v.z + v.w * v.w;
        ushort4 h;
        h.x = f2bf(v.x); h.y = f2bf(v.y); h.z = f2bf(v.z); h.w = f2bf(v.w);
        orow[l + 64 * i] = h;
    }
#pragma unroll
    for (int m = 32; m; m >>= 1) s += __shfl_xor(s, m, 64);
    if (l == 0) enorm[k] = s;
}

// ---------------- fast path kernel C: bf16 MFMA GEMM + fused chunk argmin ----------
// 128x128 tile, BK=64, XOR-swizzled LDS (chunk16 ^= row&7), pre-swizzled gload_lds src.
// Epilogue: per (row, 128-col chunk) min + 128-bit candidate mask (<= wave-min + DELTA).
__global__ __launch_bounds__(256)
void coarse_gemm_kernel(const unsigned short* __restrict__ zh,
                        const unsigned short* __restrict__ eh,
                        const float* __restrict__ enorm,
                        float* __restrict__ pmin, ulonglong2* __restrict__ pmask) {
    __shared__ __align__(16) unsigned short As[128 * 64];   // 16KB, swizzled storage
    __shared__ __align__(16) unsigned short Bs[128 * 64];   // 16KB
    __shared__ float rmin[128][2];
    __shared__ unsigned long long rmask[128][2];

    const int t = threadIdx.x;
    const int w = t >> 6, l = t & 63;
    const int wr = w & 1, wc = w >> 1;
    const int rowBase = blockIdx.x * 128;
    const int colBase = blockIdx.y * 128;

    f32x4 acc[4][4];
#pragma unroll
    for (int m = 0; m < 4; ++m)
#pragma unroll
        for (int n = 0; n < 4; ++n) acc[m][n] = (f32x4)(0.0f);

    // staging geometry: chunk id q = i*256 + t covers LDS bytes q*16.
    // row r = q>>3 = i*32 + (t>>3); stored chunk c = q&7.  Read-side swizzle is
    // c_read = c ^ (r&7), so the SOURCE for this slot is k-chunk c ^ (r&7).
    const int r0  = t >> 3;                       // 0..31
    const int csw = (t & 7) ^ (r0 & 7);           // constant across issues & k0
    const size_t zsrc = (size_t)(rowBase + r0) * ND + csw * 8;
    const size_t esrc = (size_t)(colBase + r0) * ND + csw * 8;

    for (int k0 = 0; k0 < ND; k0 += 64) {
#pragma unroll
        for (int i = 0; i < 4; ++i) {
            async16(zh + zsrc + (size_t)i * 32 * ND + k0, &As[i * 2048 + w * 512]);
            async16(eh + esrc + (size_t)i * 32 * ND + k0, &Bs[i * 2048 + w * 512]);
        }
        __syncthreads();
#pragma unroll
        for (int kk = 0; kk < 2; ++kk) {
            bf16x8 af[4], bfr[4];
#pragma unroll
            for (int m = 0; m < 4; ++m) {
                int r = wr * 64 + m * 16 + (l & 15);
                int ch = ((l >> 4) + kk * 4) ^ (l & 7);   // (r&7) == (l&7)
                af[m] = *(const bf16x8*)&As[r * 64 + ch * 8];
            }
#pragma unroll
            for (int n = 0; n < 4; ++n) {
                int r = wc * 64 + n * 16 + (l & 15);
                int ch = ((l >> 4) + kk * 4) ^ (l & 7);
                bfr[n] = *(const bf16x8*)&Bs[r * 64 + ch * 8];
            }
#pragma unroll
            for (int m = 0; m < 4; ++m)
#pragma unroll
                for (int n = 0; n < 4; ++n)
                    acc[m][n] = __builtin_amdgcn_mfma_f32_16x16x32_bf16(af[m], bfr[n], acc[m][n], 0, 0, 0);
        }
        __syncthreads();
    }

    // ---- fused epilogue: per-row wave-min + candidate masks ----
    float en[4];
#pragma unroll
    for (int n = 0; n < 4; ++n)
        en[n] = enorm[colBase + wc * 64 + n * 16 + (l & 15)];
    const int g = l >> 4;   // row group within wave

#pragma unroll
    for (int m = 0; m < 4; ++m) {
#pragma unroll
        for (int j = 0; j < 4; ++j) {
            float s[4]; float mn = 3.0e38f;
#pragma unroll
            for (int n = 0; n < 4; ++n) {
                s[n] = en[n] - 2.0f * acc[m][n][j];
                mn = fminf(mn, s[n]);
            }
#pragma unroll
            for (int d = 1; d < 16; d <<= 1) mn = fminf(mn, __shfl_xor(mn, d, 64));
            const float thr = mn + DELTA;
            unsigned long long seg = 0;
#pragma unroll
            for (int n = 0; n < 4; ++n) {
                unsigned long long bal = __ballot(s[n] <= thr);
                seg |= ((bal >> (16 * g)) & 0xFFFFull) << (n * 16);
            }
            if ((l & 15) == 0) {
                int rl = wr * 64 + m * 16 + g * 4 + j;
                rmin[rl][wc] = mn;
                rmask[rl][wc] = seg;
            }
        }
    }
    __syncthreads();
    if (t < 128) {
        float mc = fminf(rmin[t][0], rmin[t][1]);
        size_t idx = (size_t)(rowBase + t) * 8 + blockIdx.y;
        pmin[idx] = mc;
        ulonglong2 mk; mk.x = rmask[t][0]; mk.y = rmask[t][1];
        pmask[idx] = mk;
    }
}

// ---------------- fast path kernel D: resolve + gather + output + loss ----------------
// one wave per row: global min over 8 chunks, candidate list from masks,
// exact f32 rescore if >1 candidate, then stream e[bestk] -> out and accumulate loss.
__global__ __launch_bounds__(256)
void resolve_kernel(const float* __restrict__ pmin, const ulonglong2* __restrict__ pmask,
                    const float* __restrict__ z, const float* __restrict__ e,
                    const float* __restrict__ enorm, float* __restrict__ out,
                    float* __restrict__ loss) {
    __shared__ int candk[4][32];
    __shared__ int candn[4];
    const int w = threadIdx.x >> 6, l = threadIdx.x & 63;
    const int b = blockIdx.x * 4 + w;

    // global coarse min over the 8 chunks
    float v = pmin[(size_t)b * 8 + (l & 7)];
#pragma unroll
    for (int d = 1; d < 8; d <<= 1) v = fminf(v, __shfl_xor(v, d, 64));
    const float thr = v + DELTA;

    if (l == 0) {
        int cnt = 0;
#pragma unroll
        for (int c = 0; c < 8; ++c) {
            if (pmin[(size_t)b * 8 + c] <= thr) {
                ulonglong2 mk = pmask[(size_t)b * 8 + c];
                unsigned long long mm = mk.x;
                while (mm) { int bit = __ffsll((long long)mm) - 1; if (cnt < 32) candk[w][cnt] = c * 128 + bit; ++cnt; mm &= mm - 1; }
                mm = mk.y;
                while (mm) { int bit = __ffsll((long long)mm) - 1; if (cnt < 32) candk[w][cnt] = c * 128 + 64 + bit; ++cnt; mm &= mm - 1; }
            }
        }
        candn[w] = cnt > 32 ? 32 : cnt;
    }
    __syncthreads();

    const int cnt = candn[w];
    int bestk;
    if (cnt == 1) {
        bestk = candk[w][0];
    } else {
        float bestv = 3.0e38f; bestk = 0x7fffffff;
        const float4* z4 = (const float4*)(z + (size_t)b * ND);
        for (int c = 0; c < cnt; ++c) {
            int k = candk[w][c];
            const float4* e4 = (const float4*)(e + (size_t)k * ND);
            float dot = 0.f;
#pragma unroll
            for (int i = 0; i < 8; ++i) {
                float4 a = z4[l + 64 * i], bb = e4[l + 64 * i];
                dot += a.x * bb.x + a.y * bb.y + a.z * bb.z + a.w * bb.w;
            }
#pragma unroll
            for (int mm = 32; mm; mm >>= 1) dot += __shfl_xor(dot, mm, 64);
            float s = enorm[k] - 2.0f * dot;
            if (s < bestv || (s == bestv && k < bestk)) { bestv = s; bestk = k; }
        }
    }

    // stream z_q -> out, accumulate loss for this row
    const float4* q4 = (const float4*)(e + (size_t)bestk * ND);
    const float4* z4 = (const float4*)(z + (size_t)b * ND);
    float4* o4 = (float4*)(out + (size_t)b * ND);
    float accm = 0.f;
#pragma unroll
    for (int i = 0; i < 8; ++i) {
        float4 q = q4[l + 64 * i];
        float4 zz = z4[l + 64 * i];
        o4[l + 64 * i] = q;
        float dx = q.x - zz.x, dy = q.y - zz.y, dz = q.z - zz.z, dw = q.w - zz.w;
        accm += dx * dx + dy * dy + dz * dz + dw * dw;
    }
#pragma unroll
    for (int m = 32; m; m >>= 1) accm += __shfl_xor(accm, m, 64);
    __shared__ float red[4];
    if (l == 0) red[w] = accm;
    __syncthreads();
    if (threadIdx.x == 0) {
        float s = (red[0] + red[1]) + (red[2] + red[3]);
        atomicAdd(loss, s * (12.5f / 16777216.0f));
    }
}

// ---------------- fallback path (round-1, f32 VALU) ----------------
#define BK 16
#define LDS_STRIDE 20

__global__ void enorm_kernel(const float* __restrict__ e, float* __restrict__ enorm) {
    const int k = blockIdx.x;
    const int lane = threadIdx.x;
    const float4* row = (const float4*)(e + (size_t)k * ND);
    float s = 0.f;
#pragma unroll
    for (int i = 0; i < 8; ++i) {
        float4 v = row[lane + 64 * i];
        s += v.x * v.x + v.y * v.y + v.z * v.z + v.w * v.w;
    }
#pragma unroll
    for (int m = 32; m; m >>= 1) s += __shfl_xor(s, m, 64);
    if (lane == 0) enorm[k] = s;
}

__global__ __launch_bounds__(256, 2)
void argmin_kernel(const float* __restrict__ z, const float* __restrict__ e,
                   const float* __restrict__ enorm,
                   float* __restrict__ pminv, int* __restrict__ pmini) {
    __shared__ float zs[128 * LDS_STRIDE];
    __shared__ float es[128 * LDS_STRIDE];
    const int t  = threadIdx.x;
    const int tx = t & 31;
    const int ty = t >> 5;
    const int rowBase = blockIdx.x * 128;
    const int colBase = blockIdx.y * 128;

    float acc[16][4];
#pragma unroll
    for (int i = 0; i < 16; ++i)
#pragma unroll
        for (int j = 0; j < 4; ++j) acc[i][j] = 0.f;

    const int srow = t >> 2;
    const int sc4  = t & 3;

    for (int k0 = 0; k0 < ND; k0 += BK) {
#pragma unroll
        for (int q = 0; q < 2; ++q) {
            int r = srow + 64 * q;
            float4 vz = *(const float4*)(z + (size_t)(rowBase + r) * ND + k0 + sc4 * 4);
            *(float4*)(zs + r * LDS_STRIDE + sc4 * 4) = vz;
            float4 ve = *(const float4*)(e + (size_t)(colBase + r) * ND + k0 + sc4 * 4);
            *(float4*)(es + r * LDS_STRIDE + sc4 * 4) = ve;
        }
        __syncthreads();
#pragma unroll
        for (int g = 0; g < BK / 4; ++g) {
            float4 ef[4];
#pragma unroll
            for (int j = 0; j < 4; ++j)
                ef[j] = *(const float4*)(es + (tx + 32 * j) * LDS_STRIDE + g * 4);
#pragma unroll
            for (int i = 0; i < 16; ++i) {
                float4 zf = *(const float4*)(zs + (ty + 8 * i) * LDS_STRIDE + g * 4);
#pragma unroll
                for (int j = 0; j < 4; ++j) {
                    acc[i][j] += zf.x * ef[j].x;
                    acc[i][j] += zf.y * ef[j].y;
                    acc[i][j] += zf.z * ef[j].z;
                    acc[i][j] += zf.w * ef[j].w;
                }
            }
        }
        __syncthreads();
    }
#pragma unroll
    for (int i = 0; i < 16; ++i) {
        float bv = 3.0e38f; int bi = 0x7fffffff;
#pragma unroll
        for (int j = 0; j < 4; ++j) {
            int cg = colBase + tx + 32 * j;
            float s = enorm[cg] - 2.0f * acc[i][j];
            if (s < bv) { bv = s; bi = cg; }
        }
#pragma unroll
        for (int m = 16; m; m >>= 1) {
            float ov = __shfl_xor(bv, m, 64);
            int   oi = __shfl_xor(bi, m, 64);
            if (ov < bv || (ov == bv && oi < bi)) { bv = ov; bi = oi; }
        }
        if (tx == 0) {
            int r = rowBase + ty + 8 * i;
            pminv[(size_t)r * 8 + blockIdx.y] = bv;
            pmini[(size_t)r * 8 + blockIdx.y] = bi;
        }
    }
}

__global__ void final_argmin_kernel(const float* __restrict__ pminv,
                                    const int* __restrict__ pmini,
                                    int* __restrict__ ind) {
    int b = blockIdx.x * 256 + threadIdx.x;
    if (b >= NB) return;
    float bv = pminv[(size_t)b * 8];
    int   bi = pmini[(size_t)b * 8];
#pragma unroll
    for (int c = 1; c < 8; ++c) {
        float v  = pminv[(size_t)b * 8 + c];
        int   i2 = pmini[(size_t)b * 8 + c];
        if (v < bv || (v == bv && i2 < bi)) { bv = v; bi = i2; }
    }
    ind[b] = bi;
}

__global__ __launch_bounds__(256)
void gather_loss_kernel(const float* __restrict__ z, const float* __restrict__ e,
                        const int* __restrict__ ind, float* __restrict__ out,
                        float* __restrict__ loss) {
    const int NT4 = NB * ND / 4;
    float accm = 0.f;
    for (int f = blockIdx.x * blockDim.x + threadIdx.x; f < NT4;
         f += gridDim.x * blockDim.x) {
        int b  = f >> 9;
        int k4 = f & 511;
        const float4 q  = *(const float4*)(e + (size_t)ind[b] * ND + (size_t)k4 * 4);
        const float4 zz = *(const float4*)(z + (size_t)f * 4);
        *(float4*)(out + (size_t)f * 4) = q;
        float dx = q.x - zz.x, dy = q.y - zz.y, dz = q.z - zz.z, dw = q.w - zz.w;
        accm += dx * dx + dy * dy + dz * dz + dw * dw;
    }
#pragma unroll
    for (int m = 32; m; m >>= 1) accm += __shfl_xor(accm, m, 64);
    __shared__ float red[4];
    int lane = threadIdx.x & 63, w = threadIdx.x >> 6;
    if (lane == 0) red[w] = accm;
    __syncthreads();
    if (threadIdx.x == 0) {
        float s = (red[0] + red[1]) + (red[2] + red[3]);
        atomicAdd(loss, s * (12.5f / 16777216.0f));
    }
}

extern "C" void kernel_launch(void* const* d_in, const int* in_sizes, int n_in,
                              void* d_out, int out_size, void* d_ws, size_t ws_size,
                              hipStream_t stream) {
    const float* z = (const float*)d_in[0];
    const float* e = (const float*)d_in[1];
    float* out  = (float*)d_out;
    float* loss = out + (size_t)NB * ND;
    char* W = (char*)d_ws;

    const size_t OFF_ZH    = 0;                 // 32MB
    const size_t OFF_EH    = 33554432;          // 4MB
    const size_t OFF_PMIN  = 37748736;          // 256KB
    const size_t OFF_PMASK = 38010880;          // 1MB (16B aligned)
    const size_t OFF_EN    = 39059456;          // 4KB
    const size_t NEED_FAST = 39063552 + 4096;

    hipMemsetAsync(loss, 0, sizeof(float), stream);

    if (ws_size >= NEED_FAST) {
        unsigned short* zh = (unsigned short*)(W + OFF_ZH);
        unsigned short* eh = (unsigned short*)(W + OFF_EH);
        float* pmin        = (float*)(W + OFF_PMIN);
        ulonglong2* pmask  = (ulonglong2*)(W + OFF_PMASK);
        float* enorm       = (float*)(W + OFF_EN);

        hipLaunchKernelGGL(conv_z_kernel, dim3(2048), dim3(256), 0, stream, z, zh);
        hipLaunchKernelGGL(conv_e_kernel, dim3(NK), dim3(64), 0, stream, e, eh, enorm);
        hipLaunchKernelGGL(coarse_gemm_kernel, dim3(NB / 128, NK / 128), dim3(256), 0, stream,
                           zh, eh, enorm, pmin, pmask);
        hipLaunchKernelGGL(resolve_kernel, dim3(NB / 4), dim3(256), 0, stream,
                           pmin, pmask, z, e, enorm, out, loss);
    } else {
        float* enorm = (float*)W;
        float* pminv = (float*)(W + 4096);
        int*   pmini = (int*)(W + 4096 + 262144);
        int*   ind   = (int*)(W + 4096 + 524288);

        hipLaunchKernelGGL(enorm_kernel, dim3(NK), dim3(64), 0, stream, e, enorm);
        hipLaunchKernelGGL(argmin_kernel, dim3(NB / 128, NK / 128), dim3(256), 0, stream,
                           z, e, enorm, pminv, pmini);
        hipLaunchKernelGGL(final_argmin_kernel, dim3(NB / 256), dim3(256), 0, stream,
                           pminv, pmini, ind);
        hipLaunchKernelGGL(gather_loss_kernel, dim3(2048), dim3(256), 0, stream,
                           z, e, ind, out, loss);
    }
}